// Round 7
// baseline (49.856 us; speedup 1.0000x reference)
//
#include <hip/hip_runtime.h>
#include <math.h>

#define F_LEN 21
#define D_LEN 41
#define S_LEN 61                 // F_LEN + D_LEN - 1
#define ROWS 32                  // rows per tile
#define THREADS 256              // 8 threads per row
#define TILES 4                  // tiles per block (software pipeline depth)
#define NELEM (ROWS * S_LEN)     // 1952 float2 slots per tile
#define NV4   (NELEM / 4)        // 488 float4 per input array per tile
#define DOUT  (ROWS * D_LEN)     // 1312 dist floats per tile
#define DV4   (DOUT / 4)         // 328

__device__ __forceinline__ void stage_write(float2* dst, float4 f, float4 b, int idx4) {
    dst[idx4 * 4 + 0] = make_float2(f.x, b.x);
    dst[idx4 * 4 + 1] = make_float2(f.y, b.y);
    dst[idx4 * 4 + 2] = make_float2(f.z, b.z);
    dst[idx4 * 4 + 3] = make_float2(f.w, b.w);
}

// Persistent 4-tile pipeline per block:
//   iter t: [issue tile t+1 global loads] -> compute tile t from LDS buf[t&1]
//           -> moments -> distL -> ds_write tile t+1 regs into buf[(t+1)&1]
//           (vmcnt wait lands here, AFTER compute) -> barrier -> coalesced
//           dist copy-out -> barrier.
// Single statically-named reg set (f0,f1,b0,b1); all indices compile-time.
__global__ __launch_bounds__(THREADS, 4) void bp_kernel(
    const float* __restrict__ pf_g, const float* __restrict__ pb_g,
    const float* __restrict__ slop_g, const float* __restrict__ amp_g,
    float* __restrict__ out_dist, float* __restrict__ out_mean,
    float* __restrict__ out_ivar)
{
    __shared__ float2 buf[2][NELEM];      // 2 x 15616 B
    __shared__ float  distL[DOUT];        // 5248 B

    const int tid  = threadIdx.x;
    const int rl   = tid >> 3;            // local row 0..31
    const int q    = tid & 7;             // octant within row
    const int tid2 = tid + 256;           // second staging slot (if < NV4)
    const int brow = blockIdx.x * (TILES * ROWS);

    float4 f0, f1, b0, b1;
    float  aC, slC, aN, slN;

    // ---- prologue: tile 0 -> regs -> buf[0] ------------------------------
    {
        const float4* pf4 = (const float4*)(pf_g + (size_t)brow * S_LEN);
        const float4* pb4 = (const float4*)(pb_g + (size_t)brow * S_LEN);
        f0 = pf4[tid];  b0 = pb4[tid];
        if (tid2 < NV4) { f1 = pf4[tid2]; b1 = pb4[tid2]; }
        aC  = amp_g[brow + rl];
        slC = slop_g[brow + rl];
        stage_write(buf[0], f0, b0, tid);
        if (tid2 < NV4) stage_write(buf[0], f1, b1, tid2);
    }
    __syncthreads();

    #pragma unroll
    for (int t = 0; t < TILES; ++t) {
        const int row0 = brow + t * ROWS;
        const int r    = row0 + rl;

        // a. issue next tile's global loads (fly during compute)
        if (t + 1 < TILES) {
            const float4* pf4 = (const float4*)(pf_g + (size_t)(row0 + ROWS) * S_LEN);
            const float4* pb4 = (const float4*)(pb_g + (size_t)(row0 + ROWS) * S_LEN);
            f0 = pf4[tid];  b0 = pb4[tid];
            if (tid2 < NV4) { f1 = pf4[tid2]; b1 = pb4[tid2]; }
            aN  = amp_g[r + ROWS];
            slN = slop_g[r + ROWS];
        }

        // b. per-row lookup function (registers only)
        float lf[F_LEN];
        lf[10] = 0.5f;
        {
            const float E = __expf(1.0f / slC);          // slop >= 0.5
            float Ek = 1.0f;
            #pragma unroll
            for (int k = 1; k <= 10; ++k) {
                Ek *= E;
                float tnh = __fdividef(Ek - 1.0f, Ek + 1.0f);
                float dl  = aC * tnh;
                lf[10 + k] = 0.5f - dl;
                lf[10 - k] = 0.5f + dl;
            }
        }

        // c. column-streaming products from LDS buf[t&1]
        const float2* fb = buf[t & 1];
        const int  d0    = q * 5;
        const bool has6  = (q == 7);
        const int  base  = rl * S_LEN + d0;

        float prod[6] = {1.0f, 1.0f, 1.0f, 1.0f, 1.0f, 1.0f};
        #pragma unroll
        for (int i = 0; i < 26; ++i) {
            float2 v  = fb[base + i];         // one ds_read_b64
            float  df = v.x - v.y;
            #pragma unroll
            for (int dp = 0; dp < 6; ++dp) {
                const int j = i - dp;         // compile-time constant
                if (j >= 0 && j < F_LEN) {
                    float tm = fmaf(lf[j], df, v.y);
                    if (dp == 5) tm = has6 ? tm : 1.0f;
                    prod[dp] *= tm;
                }
            }
        }

        // d. moments + 8-lane butterfly
        float s0 = 0.0f, s1 = 0.0f, s2 = 0.0f;
        const float df0 = (float)d0;
        #pragma unroll
        for (int dp = 0; dp < 6; ++dp) {
            float p = prod[dp];
            if (dp == 5) p = has6 ? p : 0.0f;
            float dv = df0 + (float)dp;
            s0 += p;
            s1 += dv * p;
            s2 += dv * dv * p;
        }
        #pragma unroll
        for (int w = 1; w < 8; w <<= 1) {
            s0 += __shfl_xor(s0, w, 64);
            s1 += __shfl_xor(s1, w, 64);
            s2 += __shfl_xor(s2, w, 64);
        }

        const float inv      = 1.0f / fmaxf(s0, 1e-12f);
        const float mean_tmp = s1 * inv;
        const float m2       = s2 * inv;
        const float var_tmp  = fmaf(-mean_tmp, mean_tmp, m2);

        const float two_a = 2.0f * aC;
        const float at    = 0.5f * logf((1.0f + two_a) / (1.0f - two_a));
        const float min_v = fmaxf(0.5f / (at * at), slC);
        const float var   = fmaxf(var_tmp, min_v);

        if (q == 0) {
            out_mean[r] = mean_tmp - (float)((D_LEN - 1) / 2);
            out_ivar[r] = 1.0f / var;
        }

        // e. normalized dist -> LDS staging
        #pragma unroll
        for (int dp = 0; dp < 5; ++dp)
            distL[rl * D_LEN + d0 + dp] = prod[dp] * inv;
        if (has6)
            distL[rl * D_LEN + 40] = prod[5] * inv;

        // f. stage next tile into the other LDS buffer (vmcnt wait is here)
        if (t + 1 < TILES) {
            stage_write(buf[(t + 1) & 1], f0, b0, tid);
            if (tid2 < NV4) stage_write(buf[(t + 1) & 1], f1, b1, tid2);
            aC = aN; slC = slN;
        }
        __syncthreads();

        // g. coalesced float4 copy-out of this tile's dist
        {
            const float4* ld4 = (const float4*)distL;
            float4* o4 = (float4*)(out_dist + (size_t)row0 * D_LEN);
            o4[tid] = ld4[tid];
            if (tid2 < DV4) o4[tid2] = ld4[tid2];
        }
        __syncthreads();                      // protect distL for next tile
    }
}

extern "C" void kernel_launch(void* const* d_in, const int* in_sizes, int n_in,
                              void* d_out, int out_size, void* d_ws, size_t ws_size,
                              hipStream_t stream) {
    // inputs: [0] lines_feature (unused), [1] pf, [2] pb, [3] slop, [4] amp
    const float* pf   = (const float*)d_in[1];
    const float* pb   = (const float*)d_in[2];
    const float* slop = (const float*)d_in[3];
    const float* amp  = (const float*)d_in[4];

    const int rows = in_sizes[3];              // B * L = 131072

    float* out_dist = (float*)d_out;
    float* out_mean = out_dist + (size_t)rows * D_LEN;
    float* out_ivar = out_mean + rows;

    const int blocks = rows / (ROWS * TILES);  // 1024
    bp_kernel<<<blocks, THREADS, 0, stream>>>(pf, pb, slop, amp,
                                              out_dist, out_mean, out_ivar);
}

// Round 8
// 28.147 us; speedup vs baseline: 1.7713x; 1.7713x over previous
//
#include <hip/hip_runtime.h>
#include <math.h>

#define F_LEN 21
#define D_LEN 41
#define S_LEN 61                 // F_LEN + D_LEN - 1
#define ROWS 32                  // rows per tile
#define THREADS 256              // 8 threads per row
#define TILES 4                  // tiles per block
#define TFLOATS (ROWS * S_LEN)   // 1952 floats per array per tile
#define TPAD 2048                // padded region (floats) per array

// async global->LDS DMA, 16B per lane, dest = wave-uniform base + lane*16
__device__ __forceinline__ void gll16(const float* g, float* l) {
    __builtin_amdgcn_global_load_lds(
        (const __attribute__((address_space(1))) void*)g,
        (__attribute__((address_space(3))) void*)l, 16, 0, 0);
}

// Stage one tile (pf+pb, 1952 floats each) into linear LDS regions.
// float4 index space 0..487; wave w covers w*128 .. w*128+127 (w3 partial).
__device__ __forceinline__ void stage_tile(const float* pf_g, const float* pb_g,
                                           float* ldsF, float* ldsB,
                                           int row0, int wave, int lane) {
    const float* gf = pf_g + (size_t)row0 * S_LEN;
    const float* gb = pb_g + (size_t)row0 * S_LEN;
    const int i0 = (wave * 128 + lane) * 4;        // k=0 float idx (per-lane)
    gll16(gf + i0, ldsF + wave * 512);             // lds base wave-uniform
    gll16(gb + i0, ldsB + wave * 512);
    if (wave < 3 || lane < 40) {                   // k=1; tail chunk partial
        gll16(gf + i0 + 256, ldsF + wave * 512 + 256);
        gll16(gb + i0 + 256, ldsB + wave * 512 + 256);
    }
}

// 4-tile pipeline, register-free prefetch:
//   barrier (vmcnt drain -> buf[t] ready) -> issue gll(t+1 -> buf[t^1])
//   -> compute tile t from LDS -> direct stores -> loop.
__global__ __launch_bounds__(THREADS, 4) void bp_kernel(
    const float* __restrict__ pf_g, const float* __restrict__ pb_g,
    const float* __restrict__ slop_g, const float* __restrict__ amp_g,
    float* __restrict__ out_dist, float* __restrict__ out_mean,
    float* __restrict__ out_ivar)
{
    __shared__ float lds[2][2][TPAD];             // [buf][f/b][floats] = 32 KB

    const int tid  = threadIdx.x;
    const int wave = tid >> 6;
    const int lane = tid & 63;
    const int rl   = tid >> 3;                    // local row 0..31
    const int q    = tid & 7;                     // octant within row
    const int brow = blockIdx.x * (TILES * ROWS);

    // ---- prologue: tile 0 DMA + tile 0 scalars ---------------------------
    stage_tile(pf_g, pb_g, lds[0][0], lds[0][1], brow, wave, lane);
    float aC  = amp_g[brow + rl];
    float slC = slop_g[brow + rl];
    float aN, slN;

    #pragma unroll
    for (int t = 0; t < TILES; ++t) {
        const int row0 = brow + t * ROWS;
        const int r    = row0 + rl;

        __syncthreads();   // drains vmcnt -> buf[t&1] ready; buf[t^1] free

        // issue next tile's DMA + scalar prefetch (fly under compute)
        if (t + 1 < TILES) {
            stage_tile(pf_g, pb_g, lds[(t + 1) & 1][0], lds[(t + 1) & 1][1],
                       row0 + ROWS, wave, lane);
            aN  = amp_g[r + ROWS];
            slN = slop_g[r + ROWS];
        }

        // per-row lookup function (registers only)
        float lf[F_LEN];
        lf[10] = 0.5f;
        {
            const float E = __expf(1.0f / slC);            // slop >= 0.5
            float Ek = 1.0f;
            #pragma unroll
            for (int k = 1; k <= 10; ++k) {
                Ek *= E;
                float tnh = __fdividef(Ek - 1.0f, Ek + 1.0f);
                float dl  = aC * tnh;
                lf[10 + k] = 0.5f - dl;
                lf[10 - k] = 0.5f + dl;
            }
        }

        // column-streaming products from linear LDS
        const float* fF = lds[t & 1][0];
        const float* fB = lds[t & 1][1];
        const int  d0   = q * 5;
        const bool has6 = (q == 7);
        const int  base = rl * S_LEN + d0;

        float prod[6] = {1.0f, 1.0f, 1.0f, 1.0f, 1.0f, 1.0f};
        #pragma unroll
        for (int i = 0; i < 26; ++i) {
            float fv = fF[base + i];
            float bv = fB[base + i];
            float df = fv - bv;
            #pragma unroll
            for (int dp = 0; dp < 6; ++dp) {
                const int j = i - dp;          // compile-time constant
                if (j >= 0 && j < F_LEN) {
                    float tm = fmaf(lf[j], df, bv);
                    if (dp == 5) tm = has6 ? tm : 1.0f;
                    prod[dp] *= tm;
                }
            }
        }

        // moments + 8-lane butterfly
        float s0 = 0.0f, s1 = 0.0f, s2 = 0.0f;
        const float df0 = (float)d0;
        #pragma unroll
        for (int dp = 0; dp < 6; ++dp) {
            float p = prod[dp];
            if (dp == 5) p = has6 ? p : 0.0f;
            float dv = df0 + (float)dp;
            s0 += p;
            s1 += dv * p;
            s2 += dv * dv * p;
        }
        #pragma unroll
        for (int w = 1; w < 8; w <<= 1) {
            s0 += __shfl_xor(s0, w, 64);
            s1 += __shfl_xor(s1, w, 64);
            s2 += __shfl_xor(s2, w, 64);
        }

        const float inv      = 1.0f / fmaxf(s0, 1e-12f);
        const float mean_tmp = s1 * inv;
        const float m2       = s2 * inv;
        const float var_tmp  = fmaf(-mean_tmp, mean_tmp, m2);

        const float two_a = 2.0f * aC;
        const float at    = 0.5f * logf((1.0f + two_a) / (1.0f - two_a));
        const float min_v = fmaxf(0.5f / (at * at), slC);
        const float var   = fmaxf(var_tmp, min_v);

        if (q == 0) {
            out_mean[r] = mean_tmp - 20.0f;
            out_ivar[r] = 1.0f / var;
        }

        // direct normalized dist stores (async, drained at next barrier)
        const size_t ob = (size_t)r * D_LEN + d0;
        #pragma unroll
        for (int dp = 0; dp < 5; ++dp)
            out_dist[ob + dp] = prod[dp] * inv;
        if (has6)
            out_dist[ob + 5] = prod[5] * inv;

        aC = aN; slC = slN;
    }
}

extern "C" void kernel_launch(void* const* d_in, const int* in_sizes, int n_in,
                              void* d_out, int out_size, void* d_ws, size_t ws_size,
                              hipStream_t stream) {
    // inputs: [0] lines_feature (unused), [1] pf, [2] pb, [3] slop, [4] amp
    const float* pf   = (const float*)d_in[1];
    const float* pb   = (const float*)d_in[2];
    const float* slop = (const float*)d_in[3];
    const float* amp  = (const float*)d_in[4];

    const int rows = in_sizes[3];              // B * L = 131072

    float* out_dist = (float*)d_out;
    float* out_mean = out_dist + (size_t)rows * D_LEN;
    float* out_ivar = out_mean + rows;

    const int blocks = rows / (ROWS * TILES);  // 1024
    bp_kernel<<<blocks, THREADS, 0, stream>>>(pf, pb, slop, amp,
                                              out_dist, out_mean, out_ivar);
}